// Round 1
// 1623.406 us; speedup vs baseline: 1.0126x; 1.0126x over previous
//
#include <hip/hip_runtime.h>
#include <hip/hip_bf16.h>
#include <stdint.h>

#define T_TOK 16384
#define K_DIM 2048
#define N_DIM 8192
#define E_NUM 8

typedef __bf16 bf16x8 __attribute__((ext_vector_type(8)));
typedef float  f32x4  __attribute__((ext_vector_type(4)));
typedef unsigned short ushort8 __attribute__((ext_vector_type(8)));

__device__ __forceinline__ unsigned short f2bf(float f) {
    unsigned int u = __float_as_uint(f);
    // round-to-nearest-even
    return (unsigned short)((u + 0x7FFFu + ((u >> 16) & 1u)) >> 16);
}

__device__ __forceinline__ void async_g2l_16(void* lds, const void* g) {
    __builtin_amdgcn_global_load_lds(
        (const __attribute__((address_space(1))) unsigned int*)g,
        (__attribute__((address_space(3))) unsigned int*)lds,
        16, 0, 0);
}

// ---------------- kernel 1: x fp32 -> bf16 (elementwise) ----------------
__global__ void cvt_x_kernel(const float* __restrict__ in,
                             unsigned short* __restrict__ out) {
    size_t i = ((size_t)blockIdx.x * blockDim.x + threadIdx.x) * 8;
    float4 a = *(const float4*)(in + i);
    float4 b = *(const float4*)(in + i + 4);
    ushort8 v;
    v[0] = f2bf(a.x); v[1] = f2bf(a.y); v[2] = f2bf(a.z); v[3] = f2bf(a.w);
    v[4] = f2bf(b.x); v[5] = f2bf(b.y); v[6] = f2bf(b.z); v[7] = f2bf(b.w);
    *(ushort8*)(out + i) = v;
}

// ------- kernel 2: weight [E][K][N] fp32 -> [E][N][K] bf16 (transpose) -------
// 64x64 tile per 256-thread block.
// Loads: float4 (16B/lane, 256B per row segment). Stores: ushort8 (16B/lane,
// 8 lanes = 128B contiguous per n-row).
// LDS tile[64][73] fp32: pad 73 (==9 mod 32) makes the read-phase bank index
// (8*ox + oy + 9*dk) mod 32 -> exactly 2-way over 64 lanes (free, m136);
// write phase is also 2-way.
__global__ void transpose_w_kernel(const float* __restrict__ w,
                                   unsigned short* __restrict__ wbt) {
    __shared__ float tile[64][73];
    int e  = blockIdx.z;
    int n0 = blockIdx.x * 64;
    int k0 = blockIdx.y * 64;
    int tid = threadIdx.x;          // 0..255

    // ---- load phase: 64 (k) x 64 (n) fp32 ----
    int lx = tid & 15;              // n-chunk: 16 x float4 = 64 floats
    int ly = tid >> 4;              // k-row base: 16 rows x 4 iters
    const float* src = w + ((size_t)e * K_DIM + k0) * N_DIM + n0;
#pragma unroll
    for (int i = 0; i < 4; ++i) {
        int row = ly + 16 * i;
        float4 v = *(const float4*)(src + (size_t)row * N_DIM + lx * 4);
        tile[row][lx * 4 + 0] = v.x;
        tile[row][lx * 4 + 1] = v.y;
        tile[row][lx * 4 + 2] = v.z;
        tile[row][lx * 4 + 3] = v.w;
    }
    __syncthreads();

    // ---- store phase: 64 (n) rows x 64 (k), bf16, 16B per store ----
    int ox = tid & 7;               // k-chunk: 8 x ushort8 = 64 elems
    int oy = tid >> 3;              // n-row: 32 rows x 2 iters
    unsigned short* dst = wbt + ((size_t)e * N_DIM + n0) * K_DIM + k0 + ox * 8;
#pragma unroll
    for (int j = 0; j < 2; ++j) {
        int n = oy + 32 * j;
        ushort8 v;
#pragma unroll
        for (int dk = 0; dk < 8; ++dk)
            v[dk] = f2bf(tile[ox * 8 + dk][n]);
        *(ushort8*)(dst + (size_t)n * K_DIM) = v;
    }
}

// ---------------- kernel 3: ragged GEMM, m97 structure ----------------
// C[t,n] = sum_k xb[t,k] * wbt[e,n,k] + bias[e,n] for t in group e.
// 128x128 output tile, BK=32, 4 waves, each wave 64x64 via 4x4 MFMA 16x16x32.
__global__ void gemm_ragged_kernel(const unsigned short* __restrict__ xb,
                                   const unsigned short* __restrict__ wbt,
                                   const float* __restrict__ bias,
                                   const int* __restrict__ glist,
                                   float* __restrict__ out) {
    __shared__ __align__(16) unsigned short As[128 * 32];
    __shared__ __align__(16) unsigned short Bs[128 * 32];

    int tid  = threadIdx.x;
    int col0 = blockIdx.x * 128;

    // ---- resolve ragged row tile: expert e, rows [row0, row_hi) ----
    int r = blockIdx.y;
    int row0 = 0, gend = 0, start = 0, e = 0;
    bool found = false;
    for (e = 0; e < E_NUM; ++e) {
        int end = glist[e];
        int nt  = (end - start + 127) >> 7;
        if (r < nt) { row0 = start + (r << 7); gend = end; found = true; break; }
        r -= nt;
        start = end;
    }
    if (!found) return;   // block-uniform exit

    // ---- staging addresses: 512 chunks of 16B per tile, 2 per thread ----
    int c0 = tid, c1 = tid + 256;
    int ar0 = c0 >> 2, ak0 = (c0 & 3) * 8;   // row, k-offset (elements)
    int ar1 = c1 >> 2, ak1 = (c1 & 3) * 8;
    int gar0 = min(row0 + ar0, T_TOK - 1);   // clamp: partial tiles read valid mem
    int gar1 = min(row0 + ar1, T_TOK - 1);
    const unsigned short* gA0 = xb + (size_t)gar0 * K_DIM + ak0;
    const unsigned short* gA1 = xb + (size_t)gar1 * K_DIM + ak1;
    const unsigned short* gB0 = wbt + ((size_t)e * N_DIM + col0 + ar0) * K_DIM + ak0;
    const unsigned short* gB1 = wbt + ((size_t)e * N_DIM + col0 + ar1) * K_DIM + ak1;
    char* lA0 = (char*)As + (size_t)c0 * 16;
    char* lA1 = (char*)As + (size_t)c1 * 16;
    char* lB0 = (char*)Bs + (size_t)c0 * 16;
    char* lB1 = (char*)Bs + (size_t)c1 * 16;

    // ---- per-wave fragment addressing ----
    int wave = tid >> 6, lane = tid & 63;
    int wr = wave >> 1, wc = wave & 1;       // 2x2 wave grid over 128x128
    int lrow = lane & 15, quad = lane >> 4;
    const unsigned short* Asw = As + (wr * 64 + lrow) * 32 + quad * 8;
    const unsigned short* Bsw = Bs + (wc * 64 + lrow) * 32 + quad * 8;

    f32x4 acc[4][4] = {};

    for (int k0 = 0; k0 < K_DIM; k0 += 32) {
        __syncthreads();                      // LDS safe to overwrite
        async_g2l_16(lA0, gA0 + k0);
        async_g2l_16(lA1, gA1 + k0);
        async_g2l_16(lB0, gB0 + k0);
        async_g2l_16(lB1, gB1 + k0);
        __syncthreads();                      // drains vmcnt -> LDS visible

        bf16x8 af[4], bfr[4];
#pragma unroll
        for (int i = 0; i < 4; ++i)
            af[i] = *(const bf16x8*)(Asw + i * 16 * 32);
#pragma unroll
        for (int j = 0; j < 4; ++j)
            bfr[j] = *(const bf16x8*)(Bsw + j * 16 * 32);
#pragma unroll
        for (int i = 0; i < 4; ++i)
#pragma unroll
            for (int j = 0; j < 4; ++j)
                acc[i][j] = __builtin_amdgcn_mfma_f32_16x16x32_bf16(
                    af[i], bfr[j], acc[i][j], 0, 0, 0);
    }

    // ---- epilogue: C/D layout col=lane&15, row=quad*4+reg ----
    int row_hi = min(row0 + 128, gend);
#pragma unroll
    for (int j = 0; j < 4; ++j) {
        int col  = col0 + wc * 64 + j * 16 + lrow;
        float bv = bias[(size_t)e * N_DIM + col];
#pragma unroll
        for (int i = 0; i < 4; ++i) {
            int grow = row0 + wr * 64 + i * 16 + quad * 4;
#pragma unroll
            for (int rr = 0; rr < 4; ++rr) {
                if (grow + rr < row_hi)
                    out[(size_t)(grow + rr) * N_DIM + col] = acc[i][j][rr] + bv;
            }
        }
    }
}

extern "C" void kernel_launch(void* const* d_in, const int* in_sizes, int n_in,
                              void* d_out, int out_size, void* d_ws, size_t ws_size,
                              hipStream_t stream) {
    const float* x     = (const float*)d_in[0];
    const float* w     = (const float*)d_in[1];
    const float* bias  = (const float*)d_in[2];
    const int*   glist = (const int*)d_in[3];
    float*       out   = (float*)d_out;

    unsigned short* xb  = (unsigned short*)d_ws;                 // [T][K] bf16
    unsigned short* wbt = xb + (size_t)T_TOK * K_DIM;            // [E][N][K] bf16
    // ws needed: 2*(T*K + E*K*N) = 320 MiB

    // 1) x -> bf16
    cvt_x_kernel<<<(T_TOK * K_DIM / 8) / 256, 256, 0, stream>>>(x, xb);

    // 2) w -> bf16 transposed [E][N][K], 64x64 tiles
    dim3 tg(N_DIM / 64, K_DIM / 64, E_NUM);
    transpose_w_kernel<<<tg, 256, 0, stream>>>(w, wbt);

    // 3) ragged GEMM + bias
    dim3 gg(N_DIM / 128, T_TOK / 128 + E_NUM);   // 64 x 136 (worst-case row tiles)
    gemm_ragged_kernel<<<gg, 256, 0, stream>>>(xb, wbt, bias, glist, out);
}